// Round 20
// baseline (165.017 us; speedup 1.0000x reference)
//
#include <hip/hip_runtime.h>
#include <hip/hip_bf16.h>

constexpr int IN_DIM = 128;
constexpr int HID = 16;
constexpr int BSHIFT = 7;          // 128 dsts per bucket
constexpr int BSIZE = 1 << BSHIFT;
constexpr int CAP = 5120;          // slots per bucket (mean 4096, sigma 64)
constexpr int ECHUNK = 8192;       // edges per scatter block
constexpr int SBLK = 1024;         // scatter/fat block threads

typedef __attribute__((ext_vector_type(8))) short short8;
typedef __attribute__((ext_vector_type(4))) float f32x4;
typedef __attribute__((ext_vector_type(16))) float f32x16;
typedef __attribute__((ext_vector_type(4))) unsigned short us4;

static __device__ inline short f2bf(float x) {
    __hip_bfloat16 h = __float2bfloat16(x);
    return __builtin_bit_cast(short, h);
}
static __device__ inline float bf2f(unsigned short u) {
    unsigned int x = ((unsigned int)u) << 16;
    return __builtin_bit_cast(float, x);
}

__global__ __launch_bounds__(256) void k_init_curs(int* __restrict__ curs, int nbuck) {
    int b = blockIdx.x * 256 + threadIdx.x;
    if (b < nbuck) curs[b] = b * CAP;
}

// ---------- FAT: LDS counting-sort bin-scatter ∥ MFMA ln_xw1 ∥ prep (all 1024t) ----------
__global__ __launch_bounds__(SBLK) void k_fat(
    const int* __restrict__ src, const int* __restrict__ dst, int E,
    int* __restrict__ curs, int* __restrict__ bin, int nbuck, int nScat,
    const float* __restrict__ x, const float* __restrict__ g, const float* __restrict__ b,
    const float* __restrict__ W1, float* __restrict__ y, int N, int lnBlocks,
    const float* __restrict__ W3, const float* __restrict__ eg, const float* __restrict__ eb,
    const float* __restrict__ b3, short* __restrict__ w3f, float* __restrict__ c12) {
    __shared__ int hist[1024];               // counts -> local cursor
    __shared__ int bstart[1024];             // scan -> diff (runbase - bstart)
    __shared__ unsigned short perm[ECHUNK];  // 16 KB
    __shared__ int pkbuf[ECHUNK];            // 32 KB: packed (s<<7)|(d&127)
    __shared__ unsigned short bkbuf[ECHUNK]; // 16 KB: bucket id
    __shared__ int wsum[SBLK / 64];
    int bb = blockIdx.x;
    int t = threadIdx.x;
    if (bb < nScat) {
        // ---- scatter body: all global reads coalesced in pass 1 ----
        int base = bb * ECHUNK;
        int lim = min(ECHUNK, E - base);
        hist[t] = 0;
        __syncthreads();
        for (int i = t; i < lim; i += SBLK) {
            int d = dst[base + i];
            int s = src[base + i];
            pkbuf[i] = (s << BSHIFT) | (d & (BSIZE - 1));
            bkbuf[i] = (unsigned short)(d >> BSHIFT);
            atomicAdd(&hist[d >> BSHIFT], 1);
        }
        __syncthreads();
        {
            int lane = t & 63, wv = t >> 6;
            int v = hist[t];
            int run = v;
#pragma unroll
            for (int o = 1; o < 64; o <<= 1) {
                int u = __shfl_up(run, o);
                if (lane >= o) run += u;
            }
            if (lane == 63) wsum[wv] = run;
            __syncthreads();
            int wbase = 0;
            for (int w = 0; w < wv; ++w) wbase += wsum[w];
            bstart[t] = wbase + run - v;   // exclusive prefix
        }
        __syncthreads();
        {
            int c = hist[t];
            int bs = bstart[t];
            int rb = (c > 0 && t < nbuck) ? atomicAdd(&curs[t], c) : 0;
            hist[t] = bs;            // cursor for perm build
            bstart[t] = rb - bs;     // diff: global pos = diff + local sorted idx
        }
        __syncthreads();
        for (int i = t; i < lim; i += SBLK) {
            int bk = bkbuf[i];
            int pos = atomicAdd(&hist[bk], 1);
            perm[pos] = (unsigned short)i;
        }
        __syncthreads();
        for (int i = t; i < lim; i += SBLK) {
            int idx = perm[i];
            int bk = bkbuf[idx];
            bin[bstart[bk] + i] = pkbuf[idx];   // pure LDS -> coalesced global
        }
        return;
    }
    if (bb >= nScat + lnBlocks) {
        // ---- prep block: W3 frags in 32x32x16 A-layout: A[row=n=l&31][k=(l>>5)*8+j] ----
        int l = t;
        if (l >= 64) return;
        int n = l & 31, kh = l >> 5;
#pragma unroll
        for (int c = 0; c < 4; ++c) {
            short8 frag;
#pragma unroll
            for (int j = 0; j < 8; ++j) {
                int k = c * 16 + kh * 8 + j;
                frag[j] = f2bf(eg[k] * W3[k * 32 + n]);
            }
            *(short8*)(w3f + (size_t)(c * 64 + l) * 8) = frag;
        }
        if (l < 32) {
            float s1 = 0.f, s2 = 0.f;
            for (int j = 0; j < 64; ++j) {
                s1 += eg[j] * W3[j * 32 + l];
                s2 += eb[j] * W3[j * 32 + l];
            }
            c12[l] = s1;
            c12[32 + l] = b3[l] + s2;
        }
        return;
    }
    // ---- ln_xw1 via MFMA: 16 waves/block, one wave = 16 nodes ----
    {
        int wv = t >> 6;
        int nb = ((bb - nScat) * 16 + wv) * 16;
        if (nb >= N) return;
        int l = t & 63, gq = l >> 4, r = l & 15;
        int node = nb + r;
        bool ok = node < N;
        const float* xrow = x + (size_t)(ok ? node : 0) * IN_DIM + 8 * gq;
        float xv[4][8];
#pragma unroll
        for (int c = 0; c < 4; ++c) {
            f32x4 p0 = ok ? __builtin_nontemporal_load((const f32x4*)(xrow + 32 * c))
                          : (f32x4){0.f, 0.f, 0.f, 0.f};
            f32x4 p1 = ok ? __builtin_nontemporal_load((const f32x4*)(xrow + 32 * c + 4))
                          : (f32x4){0.f, 0.f, 0.f, 0.f};
            xv[c][0] = p0.x; xv[c][1] = p0.y; xv[c][2] = p0.z; xv[c][3] = p0.w;
            xv[c][4] = p1.x; xv[c][5] = p1.y; xv[c][6] = p1.z; xv[c][7] = p1.w;
        }
        float s = 0.f, q = 0.f;
#pragma unroll
        for (int c = 0; c < 4; ++c)
#pragma unroll
            for (int j = 0; j < 8; ++j) {
                s += xv[c][j];
                q = fmaf(xv[c][j], xv[c][j], q);
            }
        s += __shfl_xor(s, 16); s += __shfl_xor(s, 32);
        q += __shfl_xor(q, 16); q += __shfl_xor(q, 32);
        float mu = s * (1.0f / IN_DIM);
        float var = q * (1.0f / IN_DIM) - mu * mu;
        float rstd = rsqrtf(var + 1e-5f);
        f32x4 acc = {0.f, 0.f, 0.f, 0.f};
#pragma unroll
        for (int c = 0; c < 4; ++c) {
            const float* gp = g + 32 * c + 8 * gq;
            const float* bp = b + 32 * c + 8 * gq;
            const float* wp = W1 + (size_t)(32 * c + 8 * gq) * HID + r;
            short8 A, B;
#pragma unroll
            for (int j = 0; j < 8; ++j) {
                float xn = fmaf((xv[c][j] - mu) * rstd, gp[j], bp[j]);
                A[j] = f2bf(xn);
                B[j] = f2bf(wp[j * HID]);
            }
            acc = __builtin_amdgcn_mfma_f32_16x16x32_bf16(A, B, acc, 0, 0, 0);
        }
#pragma unroll
        for (int reg = 0; reg < 4; ++reg) {
            int n2 = nb + 4 * gq + reg;
            if (n2 < N) y[(size_t)n2 * HID + r] = acc[reg];
        }
    }
}

// ---------- per-bucket (1024t): degree, dinv, offs, y-scale->bf16, csr fill ----------
__global__ __launch_bounds__(1024) void k_bucket(const int* __restrict__ curs,
                                                 const int* __restrict__ bin,
                                                 float* __restrict__ dinv,
                                                 int* __restrict__ offs,
                                                 int* __restrict__ deg,
                                                 const float* __restrict__ y,
                                                 unsigned short* __restrict__ ybf,
                                                 int* __restrict__ csr, int N) {
    __shared__ int cnt[BSIZE];
    __shared__ int scn[BSIZE];
    __shared__ int tmp[BSIZE];
    __shared__ float dl[BSIZE];
    int b = blockIdx.x;
    int t = threadIdx.x;
    int lo = b * CAP;
    int hi = curs[b];
    if (t < BSIZE) cnt[t] = 0;
    __syncthreads();
    for (int i = lo + t; i < hi; i += 1024)
        atomicAdd(&cnt[bin[i] & (BSIZE - 1)], 1);
    __syncthreads();
    if (t < BSIZE) tmp[t] = cnt[t];
    __syncthreads();
#pragma unroll
    for (int o = 1; o < BSIZE; o <<= 1) {
        int v = 0;
        if (t < BSIZE && t >= o) v = tmp[t - o];
        __syncthreads();
        if (t < BSIZE) tmp[t] += v;
        __syncthreads();
    }
    int d0 = b << BSHIFT;
    if (t < BSIZE) {
        scn[t] = lo + tmp[t] - cnt[t];
        int d = d0 + t;
        if (d < N) {
            int c = cnt[t];
            float di = rsqrtf((float)(c + 1));
            dl[t] = di;
            dinv[d] = di;
            offs[d] = scn[t];
            deg[d] = c;
        }
    }
    __syncthreads();
    for (int idx = t; idx < BSIZE * HID; idx += 1024) {
        int d = d0 + (idx >> 4);
        if (d < N)
            ybf[(size_t)d * HID + (idx & 15)] =
                (unsigned short)f2bf(y[(size_t)d * HID + (idx & 15)] * dl[idx >> 4]);
    }
    for (int i = lo + t; i < hi; i += 1024) {
        int v = bin[i];
        int pos = atomicAdd(&scn[v & (BSIZE - 1)], 1);
        csr[pos] = v >> BSHIFT;
    }
}

// ---------- gather1 + xw2 fused: 4 lanes/node, 4 channels each, bf16x4 loads ----------
__global__ __launch_bounds__(256) void k_gather_xw2(const unsigned short* __restrict__ y,
                                                    const float* __restrict__ dinv,
                                                    const float* __restrict__ bias,
                                                    const int* __restrict__ offs,
                                                    const int* __restrict__ deg,
                                                    const int* __restrict__ csr,
                                                    const float* __restrict__ W2,
                                                    unsigned short* __restrict__ y2, int N) {
    int t = blockIdx.x * 256 + threadIdx.x;
    int i = t >> 2, c = t & 3;
    if (i >= N) return;
    int j0 = offs[i], j1 = j0 + deg[i];
    us4 self = *(const us4*)(y + (size_t)i * HID + 4 * c);
    float acc[4] = {bf2f(self[0]), bf2f(self[1]), bf2f(self[2]), bf2f(self[3])};
    int j = j0;
    int c0, c1, c2, c3, c4, c5, c6, c7;
    if (j + 8 <= j1) {
        c0 = csr[j];     c1 = csr[j + 1]; c2 = csr[j + 2]; c3 = csr[j + 3];
        c4 = csr[j + 4]; c5 = csr[j + 5]; c6 = csr[j + 6]; c7 = csr[j + 7];
    }
    while (j + 8 <= j1) {
        int n0 = c0, n1 = c1, n2 = c2, n3 = c3, n4 = c4, n5 = c5, n6 = c6, n7 = c7;
        int jn = j + 8;
        if (jn + 8 <= j1) {
            c0 = csr[jn];     c1 = csr[jn + 1]; c2 = csr[jn + 2]; c3 = csr[jn + 3];
            c4 = csr[jn + 4]; c5 = csr[jn + 5]; c6 = csr[jn + 6]; c7 = csr[jn + 7];
        }
        us4 a0 = *(const us4*)(y + (size_t)n0 * HID + 4 * c);
        us4 a1 = *(const us4*)(y + (size_t)n1 * HID + 4 * c);
        us4 a2 = *(const us4*)(y + (size_t)n2 * HID + 4 * c);
        us4 a3 = *(const us4*)(y + (size_t)n3 * HID + 4 * c);
        us4 a4 = *(const us4*)(y + (size_t)n4 * HID + 4 * c);
        us4 a5 = *(const us4*)(y + (size_t)n5 * HID + 4 * c);
        us4 a6 = *(const us4*)(y + (size_t)n6 * HID + 4 * c);
        us4 a7 = *(const us4*)(y + (size_t)n7 * HID + 4 * c);
#pragma unroll
        for (int q = 0; q < 4; ++q) {
            acc[q] += ((bf2f(a0[q]) + bf2f(a1[q])) + (bf2f(a2[q]) + bf2f(a3[q]))) +
                      ((bf2f(a4[q]) + bf2f(a5[q])) + (bf2f(a6[q]) + bf2f(a7[q])));
        }
        j = jn;
    }
    for (; j < j1; ++j) {
        us4 a = *(const us4*)(y + (size_t)csr[j] * HID + 4 * c);
#pragma unroll
        for (int q = 0; q < 4; ++q) acc[q] += bf2f(a[q]);
    }
    float di = dinv[i];
    float hk[4];
#pragma unroll
    for (int q = 0; q < 4; ++q) hk[q] = fmaxf(bias[4 * c + q] + di * acc[q], 0.0f);
    float acc2[4] = {0.f, 0.f, 0.f, 0.f};
#pragma unroll
    for (int cc = 0; cc < 4; ++cc) {
#pragma unroll
        for (int jj = 0; jj < 4; ++jj) {
            float hj = __shfl(hk[jj], cc, 4);
            const float* wrow = W2 + (4 * cc + jj) * 16 + 4 * c;
#pragma unroll
            for (int q = 0; q < 4; ++q) acc2[q] = fmaf(hj, wrow[q], acc2[q]);
        }
    }
    us4 o;
#pragma unroll
    for (int q = 0; q < 4; ++q) o[q] = (unsigned short)f2bf(di * acc2[q]);
    *(us4*)(y2 + (size_t)i * HID + 4 * c) = o;
}

// ---------- gather2: 4 lanes/node, 4 channels each ----------
__global__ __launch_bounds__(256) void k_gather(const unsigned short* __restrict__ y,
                                                const float* __restrict__ dinv,
                                                const float* __restrict__ bias,
                                                const int* __restrict__ offs,
                                                const int* __restrict__ deg,
                                                const int* __restrict__ csr,
                                                unsigned short* __restrict__ h, int N) {
    int t = blockIdx.x * 256 + threadIdx.x;
    int i = t >> 2, c = t & 3;
    if (i >= N) return;
    int j0 = offs[i], j1 = j0 + deg[i];
    us4 self = *(const us4*)(y + (size_t)i * HID + 4 * c);
    float acc[4] = {bf2f(self[0]), bf2f(self[1]), bf2f(self[2]), bf2f(self[3])};
    int j = j0;
    int c0, c1, c2, c3, c4, c5, c6, c7;
    if (j + 8 <= j1) {
        c0 = csr[j];     c1 = csr[j + 1]; c2 = csr[j + 2]; c3 = csr[j + 3];
        c4 = csr[j + 4]; c5 = csr[j + 5]; c6 = csr[j + 6]; c7 = csr[j + 7];
    }
    while (j + 8 <= j1) {
        int n0 = c0, n1 = c1, n2 = c2, n3 = c3, n4 = c4, n5 = c5, n6 = c6, n7 = c7;
        int jn = j + 8;
        if (jn + 8 <= j1) {
            c0 = csr[jn];     c1 = csr[jn + 1]; c2 = csr[jn + 2]; c3 = csr[jn + 3];
            c4 = csr[jn + 4]; c5 = csr[jn + 5]; c6 = csr[jn + 6]; c7 = csr[jn + 7];
        }
        us4 a0 = *(const us4*)(y + (size_t)n0 * HID + 4 * c);
        us4 a1 = *(const us4*)(y + (size_t)n1 * HID + 4 * c);
        us4 a2 = *(const us4*)(y + (size_t)n2 * HID + 4 * c);
        us4 a3 = *(const us4*)(y + (size_t)n3 * HID + 4 * c);
        us4 a4 = *(const us4*)(y + (size_t)n4 * HID + 4 * c);
        us4 a5 = *(const us4*)(y + (size_t)n5 * HID + 4 * c);
        us4 a6 = *(const us4*)(y + (size_t)n6 * HID + 4 * c);
        us4 a7 = *(const us4*)(y + (size_t)n7 * HID + 4 * c);
#pragma unroll
        for (int q = 0; q < 4; ++q) {
            acc[q] += ((bf2f(a0[q]) + bf2f(a1[q])) + (bf2f(a2[q]) + bf2f(a3[q]))) +
                      ((bf2f(a4[q]) + bf2f(a5[q])) + (bf2f(a6[q]) + bf2f(a7[q])));
        }
        j = jn;
    }
    for (; j < j1; ++j) {
        us4 a = *(const us4*)(y + (size_t)csr[j] * HID + 4 * c);
#pragma unroll
        for (int q = 0; q < 4; ++q) acc[q] += bf2f(a[q]);
    }
    float di = dinv[i];
    us4 o;
#pragma unroll
    for (int q = 0; q < 4; ++q)
        o[q] = (unsigned short)f2bf(fmaxf(bias[4 * c + q] + di * acc[q], 0.0f));
    *(us4*)(h + (size_t)i * HID + 4 * c) = o;
}

// ---------- Pair MLP via swapped 32x32x16 MFMA, dual-tile ILP ----------
__global__ __launch_bounds__(256) void k_pairs(const int* __restrict__ pa,
                                               const int* __restrict__ pb,
                                               const unsigned short* __restrict__ h2,
                                               const short* __restrict__ w3f,
                                               const float* __restrict__ c12,
                                               const float* __restrict__ W4,
                                               const float* __restrict__ b4,
                                               float* __restrict__ out,
                                               int P, int ntiles, int nwaves) {
    int wid = (blockIdx.x * 256 + threadIdx.x) >> 6;
    int l = threadIdx.x & 63;
    int p32 = l & 31;
    int kh = l >> 5;

    short8 wf0 = *(const short8*)(w3f + (size_t)(0 * 64 + l) * 8);
    short8 wf1 = *(const short8*)(w3f + (size_t)(1 * 64 + l) * 8);
    short8 wf2 = *(const short8*)(w3f + (size_t)(2 * 64 + l) * 8);
    short8 wf3 = *(const short8*)(w3f + (size_t)(3 * 64 + l) * 8);
    float c1v[16], c2v[16], w4v[16];
#pragma unroll
    for (int reg = 0; reg < 16; ++reg) {
        int n = (reg & 3) + 8 * (reg >> 2) + 4 * kh;
        c1v[reg] = c12[n];
        c2v[reg] = c12[32 + n];
        w4v[reg] = W4[n];
    }
    float b4v = b4[0];

    auto loadTile = [&](int tl, short8& u, short8& v) {
        u = (short8){0, 0, 0, 0, 0, 0, 0, 0};
        v = u;
        if (tl < ntiles) {
            int p = tl * 32 + p32;
            int pp = (p < P) ? p : 0;
            int ia = __builtin_nontemporal_load(pa + pp);
            int ib = __builtin_nontemporal_load(pb + pp);
            u = *(const short8*)(h2 + (size_t)ia * HID + 8 * kh);
            v = *(const short8*)(h2 + (size_t)ib * HID + 8 * kh);
        }
    };
    auto compute = [&](int tl, short8 ubf, short8 vbf) {
        float s = 0.f, q = 0.f;
        short8 B2, B3;
#pragma unroll
        for (int j = 0; j < 8; ++j) {
            float fu = bf2f((unsigned short)ubf[j]);
            float fv = bf2f((unsigned short)vbf[j]);
            float a2 = fabsf(fu - fv);
            float a3 = fu * fv;
            s += (fu + fv) + (a2 + a3);
            q = fmaf(fu, fu, q);
            q = fmaf(fv, fv, q);
            q = fmaf(a2, a2, q);
            q = fmaf(a3, a3, q);
            B2[j] = f2bf(a2);
            B3[j] = f2bf(a3);
        }
        s += __shfl_xor(s, 32);
        q += __shfl_xor(q, 32);
        float mu = s * (1.0f / 64.0f);
        float var = q * (1.0f / 64.0f) - mu * mu;
        float rstd = rsqrtf(var + 1e-5f);

        f32x16 d = {0.f, 0.f, 0.f, 0.f, 0.f, 0.f, 0.f, 0.f,
                    0.f, 0.f, 0.f, 0.f, 0.f, 0.f, 0.f, 0.f};
        d = __builtin_amdgcn_mfma_f32_32x32x16_bf16(wf0, ubf, d, 0, 0, 0);
        d = __builtin_amdgcn_mfma_f32_32x32x16_bf16(wf1, vbf, d, 0, 0, 0);
        d = __builtin_amdgcn_mfma_f32_32x32x16_bf16(wf2, B2, d, 0, 0, 0);
        d = __builtin_amdgcn_mfma_f32_32x32x16_bf16(wf3, B3, d, 0, 0, 0);

        float pr = 0.f;
#pragma unroll
        for (int reg = 0; reg < 16; ++reg) {
            float e = fmaxf(fmaf(rstd, fmaf(-mu, c1v[reg], d[reg]), c2v[reg]), 0.f);
            pr = fmaf(e, w4v[reg], pr);
        }
        pr += __shfl_xor(pr, 32);
        int p = tl * 32 + p32;
        if (l < 32 && p < P) out[p] = pr + b4v;
    };

    short8 uA, vA, uB, vB;
    loadTile(wid, uA, vA);
    loadTile(wid + nwaves, uB, vB);
    for (int tile = wid; tile < ntiles; tile += 2 * nwaves) {
        int tB = tile + nwaves;
        short8 uA2, vA2, uB2, vB2;
        loadTile(tile + 2 * nwaves, uA2, vA2);
        loadTile(tile + 3 * nwaves, uB2, vB2);
        compute(tile, uA, vA);
        if (tB < ntiles) compute(tB, uB, vB);
        uA = uA2; vA = vA2; uB = uB2; vB = vB2;
    }
}

extern "C" void kernel_launch(void* const* d_in, const int* in_sizes, int n_in,
                              void* d_out, int out_size, void* d_ws, size_t ws_size,
                              hipStream_t stream) {
    const float* x    = (const float*)d_in[0];
    const int*   ei   = (const int*)d_in[1];
    const int*   ep   = (const int*)d_in[2];
    const float* ln_g = (const float*)d_in[3];
    const float* ln_b = (const float*)d_in[4];
    const float* W1   = (const float*)d_in[5];
    const float* b1   = (const float*)d_in[6];
    const float* W2   = (const float*)d_in[7];
    const float* b2   = (const float*)d_in[8];
    const float* eg   = (const float*)d_in[9];
    const float* eb   = (const float*)d_in[10];
    const float* W3   = (const float*)d_in[11];
    const float* b3   = (const float*)d_in[12];
    const float* W4   = (const float*)d_in[13];
    const float* b4   = (const float*)d_in[14];
    float* out = (float*)d_out;

    const int N = in_sizes[0] / IN_DIM;
    const int E = in_sizes[1] / 2;
    const int P = in_sizes[2] / 2;
    const int* src = ei;
    const int* dst = ei + E;
    const int* pa = ep;
    const int* pb = ep + P;

    auto cdiv = [](long a, long b) { return (int)((a + b - 1) / b); };
    const int NBUCK = cdiv(N, BSIZE);
    const size_t Na = ((size_t)N + 255) & ~(size_t)255;
    const size_t binSlots = (size_t)NBUCK * CAP;

    // workspace layout
    float*          dinv = (float*)d_ws;                   // Na
    int*            degA = (int*)(dinv + Na);              // Na
    int*            offs = degA + Na;                      // Na
    int*            curs = offs + Na;                      // 1024
    float*          y    = (float*)(curs + 1024);          // N*16 f32 (unscaled)
    unsigned short* ybf  = (unsigned short*)(y + (size_t)N * HID);  // N*16 bf16
    int*            csr  = (int*)(ybf + Na * HID);         // binSlots
    int*            bin  = csr + binSlots;                 // binSlots (dead after k_bucket)
    unsigned short* y2bf = (unsigned short*)bin;           // overlay on bin
    unsigned short* h2bf = y2bf + Na * HID;                // overlay on bin
    short*          w3f  = (short*)(bin + binSlots);       // 2048 shorts
    float*          c12  = (float*)(w3f + 2048);           // 64 floats

    const int nScat = cdiv(E, ECHUNK);       // 391
    const int lnBlocks = cdiv(N, 256);       // 391 (16 waves x 16 nodes per block)

    k_init_curs<<<cdiv(NBUCK, 256), 256, 0, stream>>>(curs, NBUCK);
    k_fat<<<nScat + lnBlocks + 1, SBLK, 0, stream>>>(src, dst, E, curs, bin, NBUCK, nScat,
                                                     x, ln_g, ln_b, W1, y, N, lnBlocks,
                                                     W3, eg, eb, b3, w3f, c12);
    k_bucket<<<NBUCK, 1024, 0, stream>>>(curs, bin, dinv, offs, degA, y, ybf, csr, N);
    k_gather_xw2<<<cdiv((long)N * 4, 256), 256, 0, stream>>>(ybf, dinv, b1, offs, degA, csr, W2, y2bf, N);
    k_gather<<<cdiv((long)N * 4, 256), 256, 0, stream>>>(y2bf, dinv, b2, offs, degA, csr, h2bf, N);

    const int ntiles = cdiv(P, 32);
    const int blocks = 2048;
    const int nwaves = blocks * 4;
    k_pairs<<<blocks, 256, 0, stream>>>(pa, pb, h2bf, w3f, c12, W4, b4, out, P, ntiles, nwaves);
}

// Round 21
// 160.383 us; speedup vs baseline: 1.0289x; 1.0289x over previous
//
#include <hip/hip_runtime.h>
#include <hip/hip_bf16.h>

constexpr int IN_DIM = 128;
constexpr int HID = 16;
constexpr int BSHIFT = 7;          // 128 dsts per bucket
constexpr int BSIZE = 1 << BSHIFT;
constexpr int CAP = 5120;          // slots per bucket (mean 4096, sigma 64)
constexpr int ECHUNK = 8192;       // edges per scatter block
constexpr int SBLK = 1024;         // scatter/fat block threads

typedef __attribute__((ext_vector_type(8))) short short8;
typedef __attribute__((ext_vector_type(4))) float f32x4;
typedef __attribute__((ext_vector_type(16))) float f32x16;
typedef __attribute__((ext_vector_type(4))) unsigned short us4;

static __device__ inline short f2bf(float x) {
    __hip_bfloat16 h = __float2bfloat16(x);
    return __builtin_bit_cast(short, h);
}
static __device__ inline float bf2f(unsigned short u) {
    unsigned int x = ((unsigned int)u) << 16;
    return __builtin_bit_cast(float, x);
}

__global__ __launch_bounds__(256) void k_init_curs(int* __restrict__ curs, int nbuck) {
    int b = blockIdx.x * 256 + threadIdx.x;
    if (b < nbuck) curs[b] = b * CAP;
}

// ---------- FAT: LDS counting-sort bin-scatter ∥ MFMA ln_xw1 ∥ prep (all 1024t) ----------
__global__ __launch_bounds__(SBLK) void k_fat(
    const int* __restrict__ src, const int* __restrict__ dst, int E,
    int* __restrict__ curs, int* __restrict__ bin, int nbuck, int nScat,
    const float* __restrict__ x, const float* __restrict__ g, const float* __restrict__ b,
    const float* __restrict__ W1, float* __restrict__ y, int N, int lnBlocks,
    const float* __restrict__ W3, const float* __restrict__ eg, const float* __restrict__ eb,
    const float* __restrict__ b3, short* __restrict__ w3f, float* __restrict__ c12) {
    __shared__ int hist[1024];               // counts -> local cursor
    __shared__ int bstart[1024];             // scan -> diff (runbase - bstart)
    __shared__ unsigned short perm[ECHUNK];  // 16 KB
    __shared__ int pkbuf[ECHUNK];            // 32 KB: packed (s<<7)|(d&127)
    __shared__ unsigned short bkbuf[ECHUNK]; // 16 KB: bucket id
    __shared__ int wsum[SBLK / 64];
    int bb = blockIdx.x;
    int t = threadIdx.x;
    if (bb < nScat) {
        // ---- scatter body: all global reads coalesced in pass 1 ----
        int base = bb * ECHUNK;
        int lim = min(ECHUNK, E - base);
        hist[t] = 0;
        __syncthreads();
        for (int i = t; i < lim; i += SBLK) {
            int d = dst[base + i];
            int s = src[base + i];
            pkbuf[i] = (s << BSHIFT) | (d & (BSIZE - 1));
            bkbuf[i] = (unsigned short)(d >> BSHIFT);
            atomicAdd(&hist[d >> BSHIFT], 1);
        }
        __syncthreads();
        {
            int lane = t & 63, wv = t >> 6;
            int v = hist[t];
            int run = v;
#pragma unroll
            for (int o = 1; o < 64; o <<= 1) {
                int u = __shfl_up(run, o);
                if (lane >= o) run += u;
            }
            if (lane == 63) wsum[wv] = run;
            __syncthreads();
            int wbase = 0;
            for (int w = 0; w < wv; ++w) wbase += wsum[w];
            bstart[t] = wbase + run - v;   // exclusive prefix
        }
        __syncthreads();
        {
            int c = hist[t];
            int bs = bstart[t];
            int rb = (c > 0 && t < nbuck) ? atomicAdd(&curs[t], c) : 0;
            hist[t] = bs;            // cursor for perm build
            bstart[t] = rb - bs;     // diff: global pos = diff + local sorted idx
        }
        __syncthreads();
        for (int i = t; i < lim; i += SBLK) {
            int bk = bkbuf[i];
            int pos = atomicAdd(&hist[bk], 1);
            perm[pos] = (unsigned short)i;
        }
        __syncthreads();
        for (int i = t; i < lim; i += SBLK) {
            int idx = perm[i];
            int bk = bkbuf[idx];
            bin[bstart[bk] + i] = pkbuf[idx];   // pure LDS -> coalesced global
        }
        return;
    }
    if (bb >= nScat + lnBlocks) {
        // ---- prep block: W3 frags in 32x32x16 A-layout: A[row=n=l&31][k=(l>>5)*8+j] ----
        int l = t;
        if (l >= 64) return;
        int n = l & 31, kh = l >> 5;
#pragma unroll
        for (int c = 0; c < 4; ++c) {
            short8 frag;
#pragma unroll
            for (int j = 0; j < 8; ++j) {
                int k = c * 16 + kh * 8 + j;
                frag[j] = f2bf(eg[k] * W3[k * 32 + n]);
            }
            *(short8*)(w3f + (size_t)(c * 64 + l) * 8) = frag;
        }
        if (l < 32) {
            float s1 = 0.f, s2 = 0.f;
            for (int j = 0; j < 64; ++j) {
                s1 += eg[j] * W3[j * 32 + l];
                s2 += eb[j] * W3[j * 32 + l];
            }
            c12[l] = s1;
            c12[32 + l] = b3[l] + s2;
        }
        return;
    }
    // ---- ln_xw1 via MFMA: 16 waves/block, one wave = 16 nodes ----
    {
        int wv = t >> 6;
        int nb = ((bb - nScat) * 16 + wv) * 16;
        if (nb >= N) return;
        int l = t & 63, gq = l >> 4, r = l & 15;
        int node = nb + r;
        bool ok = node < N;
        const float* xrow = x + (size_t)(ok ? node : 0) * IN_DIM + 8 * gq;
        float xv[4][8];
#pragma unroll
        for (int c = 0; c < 4; ++c) {
            f32x4 p0 = ok ? __builtin_nontemporal_load((const f32x4*)(xrow + 32 * c))
                          : (f32x4){0.f, 0.f, 0.f, 0.f};
            f32x4 p1 = ok ? __builtin_nontemporal_load((const f32x4*)(xrow + 32 * c + 4))
                          : (f32x4){0.f, 0.f, 0.f, 0.f};
            xv[c][0] = p0.x; xv[c][1] = p0.y; xv[c][2] = p0.z; xv[c][3] = p0.w;
            xv[c][4] = p1.x; xv[c][5] = p1.y; xv[c][6] = p1.z; xv[c][7] = p1.w;
        }
        float s = 0.f, q = 0.f;
#pragma unroll
        for (int c = 0; c < 4; ++c)
#pragma unroll
            for (int j = 0; j < 8; ++j) {
                s += xv[c][j];
                q = fmaf(xv[c][j], xv[c][j], q);
            }
        s += __shfl_xor(s, 16); s += __shfl_xor(s, 32);
        q += __shfl_xor(q, 16); q += __shfl_xor(q, 32);
        float mu = s * (1.0f / IN_DIM);
        float var = q * (1.0f / IN_DIM) - mu * mu;
        float rstd = rsqrtf(var + 1e-5f);
        f32x4 acc = {0.f, 0.f, 0.f, 0.f};
#pragma unroll
        for (int c = 0; c < 4; ++c) {
            const float* gp = g + 32 * c + 8 * gq;
            const float* bp = b + 32 * c + 8 * gq;
            const float* wp = W1 + (size_t)(32 * c + 8 * gq) * HID + r;
            short8 A, B;
#pragma unroll
            for (int j = 0; j < 8; ++j) {
                float xn = fmaf((xv[c][j] - mu) * rstd, gp[j], bp[j]);
                A[j] = f2bf(xn);
                B[j] = f2bf(wp[j * HID]);
            }
            acc = __builtin_amdgcn_mfma_f32_16x16x32_bf16(A, B, acc, 0, 0, 0);
        }
#pragma unroll
        for (int reg = 0; reg < 4; ++reg) {
            int n2 = nb + 4 * gq + reg;
            if (n2 < N) y[(size_t)n2 * HID + r] = acc[reg];
        }
    }
}

// ---------- per-bucket (1024t): degree, dinv, offs, y-scale->bf16, csr fill ----------
__global__ __launch_bounds__(1024) void k_bucket(const int* __restrict__ curs,
                                                 const int* __restrict__ bin,
                                                 float* __restrict__ dinv,
                                                 int* __restrict__ offs,
                                                 int* __restrict__ deg,
                                                 const float* __restrict__ y,
                                                 unsigned short* __restrict__ ybf,
                                                 int* __restrict__ csr, int N) {
    __shared__ int cnt[BSIZE];
    __shared__ int scn[BSIZE];
    __shared__ int tmp[BSIZE];
    __shared__ float dl[BSIZE];
    int b = blockIdx.x;
    int t = threadIdx.x;
    int lo = b * CAP;
    int hi = curs[b];
    if (t < BSIZE) cnt[t] = 0;
    __syncthreads();
    for (int i = lo + t; i < hi; i += 1024)
        atomicAdd(&cnt[bin[i] & (BSIZE - 1)], 1);
    __syncthreads();
    if (t < BSIZE) tmp[t] = cnt[t];
    __syncthreads();
#pragma unroll
    for (int o = 1; o < BSIZE; o <<= 1) {
        int v = 0;
        if (t < BSIZE && t >= o) v = tmp[t - o];
        __syncthreads();
        if (t < BSIZE) tmp[t] += v;
        __syncthreads();
    }
    int d0 = b << BSHIFT;
    if (t < BSIZE) {
        scn[t] = lo + tmp[t] - cnt[t];
        int d = d0 + t;
        if (d < N) {
            int c = cnt[t];
            float di = rsqrtf((float)(c + 1));
            dl[t] = di;
            dinv[d] = di;
            offs[d] = scn[t];
            deg[d] = c;
        }
    }
    __syncthreads();
    for (int idx = t; idx < BSIZE * HID; idx += 1024) {
        int d = d0 + (idx >> 4);
        if (d < N)
            ybf[(size_t)d * HID + (idx & 15)] =
                (unsigned short)f2bf(y[(size_t)d * HID + (idx & 15)] * dl[idx >> 4]);
    }
    for (int i = lo + t; i < hi; i += 1024) {
        int v = bin[i];
        int pos = atomicAdd(&scn[v & (BSIZE - 1)], 1);
        csr[pos] = v >> BSHIFT;
    }
}

// ---------- gather1 + xw2 fused: 4 lanes/node, 4 channels each, bf16x4 loads ----------
__global__ __launch_bounds__(256) void k_gather_xw2(const unsigned short* __restrict__ y,
                                                    const float* __restrict__ dinv,
                                                    const float* __restrict__ bias,
                                                    const int* __restrict__ offs,
                                                    const int* __restrict__ deg,
                                                    const int* __restrict__ csr,
                                                    const float* __restrict__ W2,
                                                    unsigned short* __restrict__ y2, int N) {
    int t = blockIdx.x * 256 + threadIdx.x;
    int i = t >> 2, c = t & 3;
    if (i >= N) return;
    int j0 = offs[i], j1 = j0 + deg[i];
    us4 self = *(const us4*)(y + (size_t)i * HID + 4 * c);
    float acc[4] = {bf2f(self[0]), bf2f(self[1]), bf2f(self[2]), bf2f(self[3])};
    int j = j0;
    int c0, c1, c2, c3, c4, c5, c6, c7;
    if (j + 8 <= j1) {
        c0 = csr[j];     c1 = csr[j + 1]; c2 = csr[j + 2]; c3 = csr[j + 3];
        c4 = csr[j + 4]; c5 = csr[j + 5]; c6 = csr[j + 6]; c7 = csr[j + 7];
    }
    while (j + 8 <= j1) {
        int n0 = c0, n1 = c1, n2 = c2, n3 = c3, n4 = c4, n5 = c5, n6 = c6, n7 = c7;
        int jn = j + 8;
        if (jn + 8 <= j1) {
            c0 = csr[jn];     c1 = csr[jn + 1]; c2 = csr[jn + 2]; c3 = csr[jn + 3];
            c4 = csr[jn + 4]; c5 = csr[jn + 5]; c6 = csr[jn + 6]; c7 = csr[jn + 7];
        }
        us4 a0 = *(const us4*)(y + (size_t)n0 * HID + 4 * c);
        us4 a1 = *(const us4*)(y + (size_t)n1 * HID + 4 * c);
        us4 a2 = *(const us4*)(y + (size_t)n2 * HID + 4 * c);
        us4 a3 = *(const us4*)(y + (size_t)n3 * HID + 4 * c);
        us4 a4 = *(const us4*)(y + (size_t)n4 * HID + 4 * c);
        us4 a5 = *(const us4*)(y + (size_t)n5 * HID + 4 * c);
        us4 a6 = *(const us4*)(y + (size_t)n6 * HID + 4 * c);
        us4 a7 = *(const us4*)(y + (size_t)n7 * HID + 4 * c);
#pragma unroll
        for (int q = 0; q < 4; ++q) {
            acc[q] += ((bf2f(a0[q]) + bf2f(a1[q])) + (bf2f(a2[q]) + bf2f(a3[q]))) +
                      ((bf2f(a4[q]) + bf2f(a5[q])) + (bf2f(a6[q]) + bf2f(a7[q])));
        }
        j = jn;
    }
    for (; j < j1; ++j) {
        us4 a = *(const us4*)(y + (size_t)csr[j] * HID + 4 * c);
#pragma unroll
        for (int q = 0; q < 4; ++q) acc[q] += bf2f(a[q]);
    }
    float di = dinv[i];
    float hk[4];
#pragma unroll
    for (int q = 0; q < 4; ++q) hk[q] = fmaxf(bias[4 * c + q] + di * acc[q], 0.0f);
    float acc2[4] = {0.f, 0.f, 0.f, 0.f};
#pragma unroll
    for (int cc = 0; cc < 4; ++cc) {
#pragma unroll
        for (int jj = 0; jj < 4; ++jj) {
            float hj = __shfl(hk[jj], cc, 4);
            const float* wrow = W2 + (4 * cc + jj) * 16 + 4 * c;
#pragma unroll
            for (int q = 0; q < 4; ++q) acc2[q] = fmaf(hj, wrow[q], acc2[q]);
        }
    }
    us4 o;
#pragma unroll
    for (int q = 0; q < 4; ++q) o[q] = (unsigned short)f2bf(di * acc2[q]);
    *(us4*)(y2 + (size_t)i * HID + 4 * c) = o;
}

// ---------- gather2: 4 lanes/node, 4 channels each ----------
__global__ __launch_bounds__(256) void k_gather(const unsigned short* __restrict__ y,
                                                const float* __restrict__ dinv,
                                                const float* __restrict__ bias,
                                                const int* __restrict__ offs,
                                                const int* __restrict__ deg,
                                                const int* __restrict__ csr,
                                                unsigned short* __restrict__ h, int N) {
    int t = blockIdx.x * 256 + threadIdx.x;
    int i = t >> 2, c = t & 3;
    if (i >= N) return;
    int j0 = offs[i], j1 = j0 + deg[i];
    us4 self = *(const us4*)(y + (size_t)i * HID + 4 * c);
    float acc[4] = {bf2f(self[0]), bf2f(self[1]), bf2f(self[2]), bf2f(self[3])};
    int j = j0;
    int c0, c1, c2, c3, c4, c5, c6, c7;
    if (j + 8 <= j1) {
        c0 = csr[j];     c1 = csr[j + 1]; c2 = csr[j + 2]; c3 = csr[j + 3];
        c4 = csr[j + 4]; c5 = csr[j + 5]; c6 = csr[j + 6]; c7 = csr[j + 7];
    }
    while (j + 8 <= j1) {
        int n0 = c0, n1 = c1, n2 = c2, n3 = c3, n4 = c4, n5 = c5, n6 = c6, n7 = c7;
        int jn = j + 8;
        if (jn + 8 <= j1) {
            c0 = csr[jn];     c1 = csr[jn + 1]; c2 = csr[jn + 2]; c3 = csr[jn + 3];
            c4 = csr[jn + 4]; c5 = csr[jn + 5]; c6 = csr[jn + 6]; c7 = csr[jn + 7];
        }
        us4 a0 = *(const us4*)(y + (size_t)n0 * HID + 4 * c);
        us4 a1 = *(const us4*)(y + (size_t)n1 * HID + 4 * c);
        us4 a2 = *(const us4*)(y + (size_t)n2 * HID + 4 * c);
        us4 a3 = *(const us4*)(y + (size_t)n3 * HID + 4 * c);
        us4 a4 = *(const us4*)(y + (size_t)n4 * HID + 4 * c);
        us4 a5 = *(const us4*)(y + (size_t)n5 * HID + 4 * c);
        us4 a6 = *(const us4*)(y + (size_t)n6 * HID + 4 * c);
        us4 a7 = *(const us4*)(y + (size_t)n7 * HID + 4 * c);
#pragma unroll
        for (int q = 0; q < 4; ++q) {
            acc[q] += ((bf2f(a0[q]) + bf2f(a1[q])) + (bf2f(a2[q]) + bf2f(a3[q]))) +
                      ((bf2f(a4[q]) + bf2f(a5[q])) + (bf2f(a6[q]) + bf2f(a7[q])));
        }
        j = jn;
    }
    for (; j < j1; ++j) {
        us4 a = *(const us4*)(y + (size_t)csr[j] * HID + 4 * c);
#pragma unroll
        for (int q = 0; q < 4; ++q) acc[q] += bf2f(a[q]);
    }
    float di = dinv[i];
    us4 o;
#pragma unroll
    for (int q = 0; q < 4; ++q)
        o[q] = (unsigned short)f2bf(fmaxf(bias[4 * c + q] + di * acc[q], 0.0f));
    *(us4*)(h + (size_t)i * HID + 4 * c) = o;
}

// ---------- Pair MLP via swapped 32x32x16 MFMA: one wave = 32 pairs (R19 form) ----------
__global__ __launch_bounds__(256) void k_pairs(const int* __restrict__ pa,
                                               const int* __restrict__ pb,
                                               const unsigned short* __restrict__ h2,
                                               const short* __restrict__ w3f,
                                               const float* __restrict__ c12,
                                               const float* __restrict__ W4,
                                               const float* __restrict__ b4,
                                               float* __restrict__ out,
                                               int P, int ntiles, int nwaves) {
    int wid = (blockIdx.x * 256 + threadIdx.x) >> 6;
    int l = threadIdx.x & 63;
    int p32 = l & 31;
    int kh = l >> 5;

    short8 wf0 = *(const short8*)(w3f + (size_t)(0 * 64 + l) * 8);
    short8 wf1 = *(const short8*)(w3f + (size_t)(1 * 64 + l) * 8);
    short8 wf2 = *(const short8*)(w3f + (size_t)(2 * 64 + l) * 8);
    short8 wf3 = *(const short8*)(w3f + (size_t)(3 * 64 + l) * 8);
    float c1v[16], c2v[16], w4v[16];
#pragma unroll
    for (int reg = 0; reg < 16; ++reg) {
        int n = (reg & 3) + 8 * (reg >> 2) + 4 * kh;
        c1v[reg] = c12[n];
        c2v[reg] = c12[32 + n];
        w4v[reg] = W4[n];
    }
    float b4v = b4[0];

    auto loadTile = [&](int tl, short8& u, short8& v) {
        u = (short8){0, 0, 0, 0, 0, 0, 0, 0};
        v = u;
        if (tl < ntiles) {
            int p = tl * 32 + p32;
            int pp = (p < P) ? p : 0;
            int ia = __builtin_nontemporal_load(pa + pp);
            int ib = __builtin_nontemporal_load(pb + pp);
            u = *(const short8*)(h2 + (size_t)ia * HID + 8 * kh);
            v = *(const short8*)(h2 + (size_t)ib * HID + 8 * kh);
        }
    };

    short8 ubf, vbf;
    loadTile(wid, ubf, vbf);
    for (int tile = wid; tile < ntiles; tile += nwaves) {
        short8 ubf_n, vbf_n;
        loadTile(tile + nwaves, ubf_n, vbf_n);

        float s = 0.f, q = 0.f;
        short8 B2, B3;
#pragma unroll
        for (int j = 0; j < 8; ++j) {
            float fu = bf2f((unsigned short)ubf[j]);
            float fv = bf2f((unsigned short)vbf[j]);
            float a2 = fabsf(fu - fv);
            float a3 = fu * fv;
            s += (fu + fv) + (a2 + a3);
            q = fmaf(fu, fu, q);
            q = fmaf(fv, fv, q);
            q = fmaf(a2, a2, q);
            q = fmaf(a3, a3, q);
            B2[j] = f2bf(a2);
            B3[j] = f2bf(a3);
        }
        s += __shfl_xor(s, 32);
        q += __shfl_xor(q, 32);
        float mu = s * (1.0f / 64.0f);
        float var = q * (1.0f / 64.0f) - mu * mu;
        float rstd = rsqrtf(var + 1e-5f);

        f32x16 d = {0.f, 0.f, 0.f, 0.f, 0.f, 0.f, 0.f, 0.f,
                    0.f, 0.f, 0.f, 0.f, 0.f, 0.f, 0.f, 0.f};
        d = __builtin_amdgcn_mfma_f32_32x32x16_bf16(wf0, ubf, d, 0, 0, 0);
        d = __builtin_amdgcn_mfma_f32_32x32x16_bf16(wf1, vbf, d, 0, 0, 0);
        d = __builtin_amdgcn_mfma_f32_32x32x16_bf16(wf2, B2, d, 0, 0, 0);
        d = __builtin_amdgcn_mfma_f32_32x32x16_bf16(wf3, B3, d, 0, 0, 0);

        float pr = 0.f;
#pragma unroll
        for (int reg = 0; reg < 16; ++reg) {
            float e = fmaxf(fmaf(rstd, fmaf(-mu, c1v[reg], d[reg]), c2v[reg]), 0.f);
            pr = fmaf(e, w4v[reg], pr);
        }
        pr += __shfl_xor(pr, 32);
        int p = tile * 32 + p32;
        if (l < 32 && p < P) out[p] = pr + b4v;

        ubf = ubf_n;
        vbf = vbf_n;
    }
}

extern "C" void kernel_launch(void* const* d_in, const int* in_sizes, int n_in,
                              void* d_out, int out_size, void* d_ws, size_t ws_size,
                              hipStream_t stream) {
    const float* x    = (const float*)d_in[0];
    const int*   ei   = (const int*)d_in[1];
    const int*   ep   = (const int*)d_in[2];
    const float* ln_g = (const float*)d_in[3];
    const float* ln_b = (const float*)d_in[4];
    const float* W1   = (const float*)d_in[5];
    const float* b1   = (const float*)d_in[6];
    const float* W2   = (const float*)d_in[7];
    const float* b2   = (const float*)d_in[8];
    const float* eg   = (const float*)d_in[9];
    const float* eb   = (const float*)d_in[10];
    const float* W3   = (const float*)d_in[11];
    const float* b3   = (const float*)d_in[12];
    const float* W4   = (const float*)d_in[13];
    const float* b4   = (const float*)d_in[14];
    float* out = (float*)d_out;

    const int N = in_sizes[0] / IN_DIM;
    const int E = in_sizes[1] / 2;
    const int P = in_sizes[2] / 2;
    const int* src = ei;
    const int* dst = ei + E;
    const int* pa = ep;
    const int* pb = ep + P;

    auto cdiv = [](long a, long b) { return (int)((a + b - 1) / b); };
    const int NBUCK = cdiv(N, BSIZE);
    const size_t Na = ((size_t)N + 255) & ~(size_t)255;
    const size_t binSlots = (size_t)NBUCK * CAP;

    // workspace layout
    float*          dinv = (float*)d_ws;                   // Na
    int*            degA = (int*)(dinv + Na);              // Na
    int*            offs = degA + Na;                      // Na
    int*            curs = offs + Na;                      // 1024
    float*          y    = (float*)(curs + 1024);          // N*16 f32 (unscaled)
    unsigned short* ybf  = (unsigned short*)(y + (size_t)N * HID);  // N*16 bf16
    int*            csr  = (int*)(ybf + Na * HID);         // binSlots
    int*            bin  = csr + binSlots;                 // binSlots (dead after k_bucket)
    unsigned short* y2bf = (unsigned short*)bin;           // overlay on bin
    unsigned short* h2bf = y2bf + Na * HID;                // overlay on bin
    short*          w3f  = (short*)(bin + binSlots);       // 2048 shorts
    float*          c12  = (float*)(w3f + 2048);           // 64 floats

    const int nScat = cdiv(E, ECHUNK);       // 391
    const int lnBlocks = cdiv(N, 256);       // 391 (16 waves x 16 nodes per block)

    k_init_curs<<<cdiv(NBUCK, 256), 256, 0, stream>>>(curs, NBUCK);
    k_fat<<<nScat + lnBlocks + 1, SBLK, 0, stream>>>(src, dst, E, curs, bin, NBUCK, nScat,
                                                     x, ln_g, ln_b, W1, y, N, lnBlocks,
                                                     W3, eg, eb, b3, w3f, c12);
    k_bucket<<<NBUCK, 1024, 0, stream>>>(curs, bin, dinv, offs, degA, y, ybf, csr, N);
    k_gather_xw2<<<cdiv((long)N * 4, 256), 256, 0, stream>>>(ybf, dinv, b1, offs, degA, csr, W2, y2bf, N);
    k_gather<<<cdiv((long)N * 4, 256), 256, 0, stream>>>(y2bf, dinv, b2, offs, degA, csr, h2bf, N);

    const int ntiles = cdiv(P, 32);
    const int blocks = 2048;
    const int nwaves = blocks * 4;
    k_pairs<<<blocks, 256, 0, stream>>>(pa, pb, h2bf, w3f, c12, W4, b4, out, P, ntiles, nwaves);
}